// Round 15
// baseline (122.144 us; speedup 1.0000x reference)
//
#include <hip/hip_runtime.h>
#include <hip/hip_bf16.h>

#define TB 256

typedef __attribute__((ext_vector_type(8))) short short8;
typedef __attribute__((ext_vector_type(4))) unsigned int uint4v;
typedef __attribute__((ext_vector_type(4))) float f32x4;

// Problem constants: B=16, C=64, L=16384, HOP=256, KS=3, DIL=3, KL=64
// ws: ktf u32[16 b][96 chunk][64 f][128 slot] = 50,331,648 B  (chunk=(kk*4+jp)*4+hi)
//     wf  u32[6144]                            = 24,576 B
#define KTF_BYTES 50331648ull
#define WS_NEED   (KTF_BYTES + 24576ull)

static __device__ __forceinline__ float lrelu(float v){ return v > 0.f ? v : 0.2f*v; }

static __device__ __forceinline__ unsigned int pack2(float lo, float hi){
    __hip_bfloat162 h = __float22bfloat162_rn(float2{lo, hi});
    unsigned int r;
    __builtin_memcpy(&r, &h, 4);
    return r;
}

static __device__ __forceinline__ float bf2f(unsigned int u16v){
    return __uint_as_float(u16v << 16);
}

// sigmoid(a)*tanh(t) = (v-1) / ((1+u)(v+1)),  u=e^-a, v=e^{2t}
static __device__ __forceinline__ float glu_gate(float a, float t){
    float u = __expf(-a);
    float v = __expf(2.0f * t);
    float den = (1.0f + u) * (v + 1.0f);
    return (v - 1.0f) * __builtin_amdgcn_rcpf(den);
}

// ---------------------------------------------------------------------------
// A-frag pair: u32 = bf16{A[ch][r], A[ch][r+1]}, r = kk*32 + hi*8 + 2jp
// slot s = mt*16 + row; GLU same-lane map (mt 0..7):
//   row&2==0 -> sigmoid ch = mt*8 + 2*(row>>2) + (row&1)
//   row&2==2 -> tanh    ch = 64 + mt*8 + 2*(row>>2) + (row&1)
// ktf addr: ((b*96 + (kk*4+jp)*4 + hi)*64 + f)*128 + slot

__global__ __launch_bounds__(256, 4)
void ktf_transpose(const float* __restrict__ kern, unsigned int* __restrict__ ktf)
{
    __shared__ unsigned int tl32[128 * 65];            // [oc][f pad65], 33280 B
    const int tid = threadIdx.x;
    const int blk = blockIdx.x;                        // 1536 = b*96 + ci2*3 + k
    const int k   = blk % 3;
    const int ci2 = (blk / 3) % 32;
    const int b   = blk / 96;
    const int kk  = k*2 + (ci2 >> 4);
    const int hi  = (ci2 >> 2) & 3;
    const int jp  = ci2 & 3;

    const float* src0 = kern + (size_t)b*1572864 + (size_t)ci2*49152 + k*64;
    #pragma unroll
    for (int it = 0; it < 8; ++it) {
        int p = tid + it*TB;                           // 2048 = 128 oc * 16 fq
        int oc = p >> 4, fq = p & 15;
        const float* s = src0 + oc*192 + fq*4;
        float4 v0 = *(const float4*)(s);               // ci even
        float4 v1 = *(const float4*)(s + 24576);       // ci odd
        unsigned int* d = tl32 + oc*65 + fq*4;
        d[0] = pack2(v0.x, v1.x);
        d[1] = pack2(v0.y, v1.y);
        d[2] = pack2(v0.z, v1.z);
        d[3] = pack2(v0.w, v1.w);
    }
    __syncthreads();

    const int l = tid & 63, wvv = tid >> 6;
    const int c = (kk*4 + jp)*4 + hi;
    const int oc0 = 2*l;                               // even channel
    const int slot0 = (oc0 < 64)
        ? ((oc0 >> 3)*16 + ((oc0 & 7) >> 1)*4)
        : (((oc0 - 64) >> 3)*16 + (((oc0 - 64) & 7) >> 1)*4 + 2);
    unsigned int* dst = ktf + (size_t)(b*96 + c)*8192 + slot0;
    const int f0 = wvv*16;
    #pragma unroll
    for (int fi = 0; fi < 16; ++fi) {
        int f = f0 + fi;
        uint2 v;
        v.x = tl32[(oc0    )*65 + f];
        v.y = tl32[(oc0 + 1)*65 + f];
        *(uint2*)(dst + f*128) = v;
    }
}

// conv_w[co][ci][k] -> wf (conv A-frags, plain m = mt*16+lo mapping)
__global__ __launch_bounds__(256, 4)
void wf_prep(const float* __restrict__ conv_w, unsigned int* __restrict__ wf)
{
    int u = blockIdx.x*TB + threadIdx.x;               // 6144
    int ln = u & 63, mt = (u >> 6) & 3, jp = (u >> 8) & 3, kk = u >> 10;
    int lo = ln & 15, hi = ln >> 4;
    int m  = mt*16 + lo;
    int k  = kk >> 1, ci = (kk & 1)*32 + hi*8 + jp*2;
    float a0 = conv_w[m*192 + ci*3 + k];
    float a1 = conv_w[m*192 + (ci + 1)*3 + k];
    wf[u] = pack2(a0, a1);
}

// ---------------------------------------------------------------------------
// LDS: xt[144][64ci] bf16 swizzled @0 (18432B)
//      ht[144][64]   bf16 swizzled @18432 (18432B)
//      bias_lds[128] f32 @36864 (512B)  -> 37376 B total
#define LDS_HT   18432
#define LDS_BIAS 36864

__global__ __launch_bounds__(512, 6)
void fused_kernel(const float* __restrict__ x,
                  const float* __restrict__ bias,
                  const float* __restrict__ conv_b,
                  const unsigned int* __restrict__ ktf,
                  const unsigned int* __restrict__ wf,
                  float* __restrict__ out)
{
    __shared__ char lds[37376];
    float* bias_lds = (float*)(lds + LDS_BIAS);

    const int tid = threadIdx.x;
    const int blk = blockIdx.x;                        // 2048 = (b*64+f)*2 + h
    const int h  = blk & 1;                            // halves adjacent -> ktf L2-shared
    const int bf = blk >> 1;
    const int b = bf >> 6, f = bf & 63;
    const int tb = (f << 8) + h*128;                   // this block's 128 positions
    const int ln = tid & 63, wv = tid >> 6;            // 8 waves
    const int lo = ln & 15, hi = ln >> 4;

    if (tid < 128) bias_lds[tid] = bias[(size_t)b*8192 + tid*64 + f];

    // ---- A: load x half-tile (transposed, lrelu, bf16) -> xt[144][64] ----
    {
        const float* xb = x + ((size_t)b*64 + wv*8) * 16384;  // wave's ci octet
        const int ts = tb - 12;                        // xt row q <-> t = ts + q
        const bool interior = (ts >= 0) & (ts + 143 < 16384);
        #pragma unroll
        for (int it = 0; it < 3; ++it) {
            int p = (it < 2) ? (ln + it*64) : (128 + ln);
            if (it < 2 || ln < 16) {
                int t = ts + p;
                float v[8];
                if (interior) {
                    #pragma unroll
                    for (int j = 0; j < 8; ++j) v[j] = xb[j*16384 + t];
                } else {
                    bool ok = (unsigned)t < 16384u;
                    #pragma unroll
                    for (int j = 0; j < 8; ++j) v[j] = ok ? xb[j*16384 + t] : 0.f;
                }
                unsigned int w0 = pack2(lrelu(v[0]), lrelu(v[1]));
                unsigned int w1 = pack2(lrelu(v[2]), lrelu(v[3]));
                unsigned int w2 = pack2(lrelu(v[4]), lrelu(v[5]));
                unsigned int w3 = pack2(lrelu(v[6]), lrelu(v[7]));
                int a = (p*128 + wv*16) ^ ((p & 7) << 4);
                *(uint4*)(lds + a) = make_uint4(w0, w1, w2, w3);
            }
        }
    }
    __syncthreads();

    // ---- B: dilated conv; wave (mp=wv&1 -> m-tiles {2mp,2mp+1}, nq=wv>>1) ----
    {
        const int mp = wv & 1, nq = wv >> 1;
        const int mtA = 2*mp, mtB = 2*mp + 1;
        uint4v aw0[6], aw1[6];
        #pragma unroll
        for (int kk = 0; kk < 6; ++kk) {
            int w0 = kk*1024 + mtA*64 + ln;
            aw0[kk].x = wf[w0      ]; aw0[kk].y = wf[w0 + 256];
            aw0[kk].z = wf[w0 + 512]; aw0[kk].w = wf[w0 + 768];
            aw1[kk].x = wf[w0 +  64]; aw1[kk].y = wf[w0 + 320];
            aw1[kk].z = wf[w0 + 576]; aw1[kk].w = wf[w0 + 832];
        }
        float4 cbA = *(const float4*)(conv_b + mtA*16 + hi*4);
        float4 cbB = *(const float4*)(conv_b + mtB*16 + hi*4);
        const int n0  = (nq == 0) ? 0 : (2*nq + 1);    // nt: {0,1,2},{3,4},{5,6},{7,8}
        const int cnt = (nq == 0) ? 3 : 2;
        int bqa[6];
        #pragma unroll
        for (int kk = 0; kk < 6; ++kk) {
            int row = n0*16 + lo + 3*(kk >> 1) + 1;
            int cib = (kk & 1)*32 + hi*8;
            bqa[kk] = (row*128 + cib*2) ^ ((row & 7) << 4);
        }
        int htaA = LDS_HT + (((n0*16 + lo)*128 + (mtA*16 + hi*4)*2) ^ ((lo & 7) << 4));
        int htaB = LDS_HT + (((n0*16 + lo)*128 + (mtB*16 + hi*4)*2) ^ ((lo & 7) << 4));
        int pos  = tb + n0*16 + lo - 8;
        #pragma unroll 1
        for (int i = 0; i < cnt; ++i) {
            f32x4 accA = {0.f,0.f,0.f,0.f}, accB = {0.f,0.f,0.f,0.f};
            __builtin_amdgcn_s_setprio(1);
            #pragma unroll
            for (int kk = 0; kk < 6; ++kk) {
                short8 bq = *(const short8*)(lds + bqa[kk]);
                accA = __builtin_amdgcn_mfma_f32_16x16x32_bf16(
                        __builtin_bit_cast(short8, aw0[kk]), bq, accA, 0, 0, 0);
                accB = __builtin_amdgcn_mfma_f32_16x16x32_bf16(
                        __builtin_bit_cast(short8, aw1[kk]), bq, accB, 0, 0, 0);
            }
            __builtin_amdgcn_s_setprio(0);

            bool valid = (unsigned)pos < 16384u;
            unsigned int* dA = (unsigned int*)(lds + htaA);
            dA[0] = valid ? pack2(lrelu(accA[0] + cbA.x), lrelu(accA[1] + cbA.y)) : 0u;
            dA[1] = valid ? pack2(lrelu(accA[2] + cbA.z), lrelu(accA[3] + cbA.w)) : 0u;
            unsigned int* dB = (unsigned int*)(lds + htaB);
            dB[0] = valid ? pack2(lrelu(accB[0] + cbB.x), lrelu(accB[1] + cbB.y)) : 0u;
            dB[1] = valid ? pack2(lrelu(accB[2] + cbB.z), lrelu(accB[3] + cbB.w)) : 0u;

            #pragma unroll
            for (int kk = 0; kk < 6; ++kk) bqa[kk] += 2048;
            htaA += 2048; htaB += 2048; pos += 16;
        }
    }
    __syncthreads();

    // ---- C: LVC; wave (mtA=wv&3 -> m-tiles {mtA,mtA+4}, nh=wv>>2) ----
    {
        const int mtA = wv & 3, nh = wv >> 2;
        uint4v am0[6], am1[6];
        const unsigned int* kp = ktf + (size_t)b*786432 + hi*8192 + f*128 + mtA*16 + lo;
        #pragma unroll
        for (int kk = 0; kk < 6; ++kk) {
            int o = kk*131072;                         // jp stride 32768
            am0[kk].x = kp[o         ]; am0[kk].y = kp[o + 32768];
            am0[kk].z = kp[o +  65536]; am0[kk].w = kp[o + 98304];
            am1[kk].x = kp[o +     64]; am1[kk].y = kp[o + 32832];
            am1[kk].z = kp[o +  65600]; am1[kk].w = kp[o + 98368];
        }
        const int ch2A = mtA*8 + 2*hi;                 // m-tile mtA's channel pair
        const int ch2B = ch2A + 32;                    // m-tile mtA+4's
        float bsA0 = bias_lds[ch2A],      bsA1 = bias_lds[ch2A + 1];
        float btA0 = bias_lds[ch2A + 64], btA1 = bias_lds[ch2A + 65];
        float bsB0 = bias_lds[ch2B],      bsB1 = bias_lds[ch2B + 1];
        float btB0 = bias_lds[ch2B + 64], btB1 = bias_lds[ch2B + 65];

        int bqa[6];
        #pragma unroll
        for (int kk = 0; kk < 6; ++kk) {
            int row = nh*64 + lo + 7 + (kk >> 1);
            int cib = (kk & 1)*32 + hi*8;
            bqa[kk] = LDS_HT + ((row*128 + cib*2) ^ ((row & 7) << 4));
        }
        int q   = nh*64 + lo + 12;
        int raA = (q*128 + ch2A*2) ^ ((q & 7) << 4);
        int raB = (q*128 + ch2B*2) ^ ((q & 7) << 4);
        float* obA = out + ((size_t)b*64 + ch2A)*16384 + tb + nh*64 + lo;
        float* obB = obA + (size_t)32*16384;

        #pragma unroll 1
        for (int i = 0; i < 4; ++i) {
            f32x4 accA = {0.f,0.f,0.f,0.f}, accB = {0.f,0.f,0.f,0.f};
            __builtin_amdgcn_s_setprio(1);
            #pragma unroll
            for (int kk = 0; kk < 6; ++kk) {
                short8 bq = *(const short8*)(lds + bqa[kk]);
                accA = __builtin_amdgcn_mfma_f32_16x16x32_bf16(
                        __builtin_bit_cast(short8, am0[kk]), bq, accA, 0, 0, 0);
                accB = __builtin_amdgcn_mfma_f32_16x16x32_bf16(
                        __builtin_bit_cast(short8, am1[kk]), bq, accB, 0, 0, 0);
            }
            __builtin_amdgcn_s_setprio(0);

            unsigned int rvA = *(const unsigned int*)(lds + raA);
            unsigned int rvB = *(const unsigned int*)(lds + raB);
            float hA0 = bf2f(rvA & 0xFFFFu), hA1 = bf2f(rvA >> 16);
            float hB0 = bf2f(rvB & 0xFFFFu), hB1 = bf2f(rvB >> 16);

            float gA0 = glu_gate(accA[0] + bsA0, accA[2] + btA0);
            float gA1 = glu_gate(accA[1] + bsA1, accA[3] + btA1);
            float gB0 = glu_gate(accB[0] + bsB0, accB[2] + btB0);
            float gB1 = glu_gate(accB[1] + bsB1, accB[3] + btB1);

            obA[(size_t)i*16]         = fminf(hA0, 5.0f*hA0) + gA0;
            obA[16384 + (size_t)i*16] = fminf(hA1, 5.0f*hA1) + gA1;
            obB[(size_t)i*16]         = fminf(hB0, 5.0f*hB0) + gB0;
            obB[16384 + (size_t)i*16] = fminf(hB1, 5.0f*hB1) + gB1;

            #pragma unroll
            for (int kk = 0; kk < 6; ++kk) bqa[kk] += 2048;
            raA += 2048; raB += 2048;
        }
    }
}

extern "C" void kernel_launch(void* const* d_in, const int* in_sizes, int n_in,
                              void* d_out, int out_size, void* d_ws, size_t ws_size,
                              hipStream_t stream)
{
    const float* x      = (const float*)d_in[0];
    const float* kern   = (const float*)d_in[1];
    const float* bias   = (const float*)d_in[2];
    const float* conv_b = (const float*)d_in[4];
    float* out = (float*)d_out;

    if (ws_size < WS_NEED) return;   // harness provides >=100MB (verified R0)

    unsigned int* ktf = (unsigned int*)d_ws;
    unsigned int* wf  = (unsigned int*)((char*)d_ws + KTF_BYTES);

    wf_prep      <<<dim3(24),   dim3(TB), 0, stream>>>((const float*)d_in[3], wf);
    ktf_transpose<<<dim3(1536), dim3(TB), 0, stream>>>(kern, ktf);
    fused_kernel <<<dim3(2048), dim3(512), 0, stream>>>(x, bias, conv_b, ktf, wf, out);
    (void)in_sizes; (void)n_in; (void)out_size;
}

// Round 16
// 86.153 us; speedup vs baseline: 1.4178x; 1.4178x over previous
//
#include <hip/hip_runtime.h>
#include <hip/hip_bf16.h>

#define TB 256

typedef __attribute__((ext_vector_type(8))) short short8;
typedef __attribute__((ext_vector_type(4))) unsigned int uint4v;
typedef __attribute__((ext_vector_type(4))) float f32x4;

// Problem constants: B=16, C=64, L=16384, HOP=256, KS=3, DIL=3, KL=64
// ws: ktf u32[16 b][96 chunk][64 f][128 slot] = 50,331,648 B  (chunk=(kk*4+jp)*4+hi)
//     wf  u32[6144]                            = 24,576 B
#define KTF_BYTES 50331648ull
#define WS_NEED   (KTF_BYTES + 24576ull)

static __device__ __forceinline__ float lrelu(float v){ return v > 0.f ? v : 0.2f*v; }

static __device__ __forceinline__ unsigned int pack2(float lo, float hi){
    __hip_bfloat162 h = __float22bfloat162_rn(float2{lo, hi});
    unsigned int r;
    __builtin_memcpy(&r, &h, 4);
    return r;
}

static __device__ __forceinline__ float bf2f(unsigned int u16v){
    return __uint_as_float(u16v << 16);
}

// sigmoid(a)*tanh(t) = (v-1) / ((1+u)(v+1)),  u=e^-a, v=e^{2t}
static __device__ __forceinline__ float glu_gate(float a, float t){
    float u = __expf(-a);
    float v = __expf(2.0f * t);
    float den = (1.0f + u) * (v + 1.0f);
    return (v - 1.0f) * __builtin_amdgcn_rcpf(den);
}

// ---------------------------------------------------------------------------
// A-frag pair: u32 = bf16{A[ch][r], A[ch][r+1]}, r = kk*32 + hi*8 + 2jp
// slot s = mt*16 + row; GLU same-lane map (mt 0..7):
//   row&2==0 -> sigmoid ch = mt*8 + 2*(row>>2) + (row&1)
//   row&2==2 -> tanh    ch = 64 + mt*8 + 2*(row>>2) + (row&1)
// ktf addr: ((b*96 + (kk*4+jp)*4 + hi)*64 + f)*128 + slot

__global__ __launch_bounds__(256, 4)
void ktf_transpose(const float* __restrict__ kern, unsigned int* __restrict__ ktf)
{
    __shared__ unsigned int tl32[128 * 65];            // [oc][f pad65], 33280 B
    const int tid = threadIdx.x;
    const int blk = blockIdx.x;                        // 1536 = b*96 + ci2*3 + k
    const int k   = blk % 3;
    const int ci2 = (blk / 3) % 32;
    const int b   = blk / 96;
    const int kk  = k*2 + (ci2 >> 4);
    const int hi  = (ci2 >> 2) & 3;
    const int jp  = ci2 & 3;

    const float* src0 = kern + (size_t)b*1572864 + (size_t)ci2*49152 + k*64;
    #pragma unroll
    for (int it = 0; it < 8; ++it) {
        int p = tid + it*TB;                           // 2048 = 128 oc * 16 fq
        int oc = p >> 4, fq = p & 15;
        const float* s = src0 + oc*192 + fq*4;
        float4 v0 = *(const float4*)(s);               // ci even
        float4 v1 = *(const float4*)(s + 24576);       // ci odd
        unsigned int* d = tl32 + oc*65 + fq*4;
        d[0] = pack2(v0.x, v1.x);
        d[1] = pack2(v0.y, v1.y);
        d[2] = pack2(v0.z, v1.z);
        d[3] = pack2(v0.w, v1.w);
    }
    __syncthreads();

    const int l = tid & 63, wvv = tid >> 6;
    const int c = (kk*4 + jp)*4 + hi;
    const int oc0 = 2*l;                               // even channel
    const int slot0 = (oc0 < 64)
        ? ((oc0 >> 3)*16 + ((oc0 & 7) >> 1)*4)
        : (((oc0 - 64) >> 3)*16 + (((oc0 - 64) & 7) >> 1)*4 + 2);
    unsigned int* dst = ktf + (size_t)(b*96 + c)*8192 + slot0;
    const int f0 = wvv*16;
    #pragma unroll
    for (int fi = 0; fi < 16; ++fi) {
        int f = f0 + fi;
        uint2 v;
        v.x = tl32[(oc0    )*65 + f];
        v.y = tl32[(oc0 + 1)*65 + f];
        *(uint2*)(dst + f*128) = v;
    }
}

// conv_w[co][ci][k] -> wf (conv A-frags, plain m = mt*16+lo mapping)
__global__ __launch_bounds__(256, 4)
void wf_prep(const float* __restrict__ conv_w, unsigned int* __restrict__ wf)
{
    int u = blockIdx.x*TB + threadIdx.x;               // 6144
    int ln = u & 63, mt = (u >> 6) & 3, jp = (u >> 8) & 3, kk = u >> 10;
    int lo = ln & 15, hi = ln >> 4;
    int m  = mt*16 + lo;
    int k  = kk >> 1, ci = (kk & 1)*32 + hi*8 + jp*2;
    float a0 = conv_w[m*192 + ci*3 + k];
    float a1 = conv_w[m*192 + (ci + 1)*3 + k];
    wf[u] = pack2(a0, a1);
}

// ---------------------------------------------------------------------------
// LDS: xt[144][64ci] bf16 swizzled @0 (18432B)
//      ht[144][64]   bf16 swizzled @18432 (18432B)
//      bias_lds[128] f32 @36864 (512B)  -> 37376 B total
#define LDS_HT   18432
#define LDS_BIAS 36864

__global__ __launch_bounds__(512, 5)
void fused_kernel(const float* __restrict__ x,
                  const float* __restrict__ bias,
                  const float* __restrict__ conv_b,
                  const unsigned int* __restrict__ ktf,
                  const unsigned int* __restrict__ wf,
                  float* __restrict__ out)
{
    __shared__ char lds[37376];
    float* bias_lds = (float*)(lds + LDS_BIAS);

    const int tid = threadIdx.x;
    const int blk = blockIdx.x;                        // 2048 = (b*64+f)*2 + h
    const int h = blk & 1;
    const int bf = blk >> 1;
    const int b = bf >> 6, f = bf & 63;
    const int tb = (f << 8) + h*128;                   // this block's 128 positions
    const int ln = tid & 63, wv = tid >> 6;            // 8 waves
    const int lo = ln & 15, hi = ln >> 4;
    const int mt = wv & 3, nth = wv >> 2;

    // ---- A1: issue x loads FIRST (oldest in vmcnt order); float2/lane ----
    const float* xb = x + ((size_t)b*64 + wv*8) * 16384;
    const int ts = tb - 12;
    float2 xv[2][8];
    {
        const bool interior = (ts >= 0) & (ts + 143 < 16384);
        if (interior) {
            #pragma unroll
            for (int it = 0; it < 2; ++it) {
                if (it == 0 || ln < 8) {
                    int t = ts + 2*ln + it*128;
                    #pragma unroll
                    for (int j = 0; j < 8; ++j)
                        xv[it][j] = *(const float2*)(xb + j*16384 + t);
                }
            }
        } else {
            #pragma unroll
            for (int it = 0; it < 2; ++it) {
                if (it == 0 || ln < 8) {
                    int t = ts + 2*ln + it*128;
                    #pragma unroll
                    for (int j = 0; j < 8; ++j) {
                        float a0 = ((unsigned)t       < 16384u) ? xb[j*16384 + t    ] : 0.f;
                        float a1 = ((unsigned)(t + 1) < 16384u) ? xb[j*16384 + t + 1] : 0.f;
                        xv[it][j] = make_float2(a0, a1);
                    }
                }
            }
        }
    }
    __builtin_amdgcn_sched_barrier(0);

    // ---- A2: issue aw loads (phase B A-frags) + bias ----
    uint4v aw[6];
    #pragma unroll
    for (int kk = 0; kk < 6; ++kk) {
        int w0 = kk*1024 + mt*64 + ln;
        aw[kk].x = wf[w0      ]; aw[kk].y = wf[w0 + 256];
        aw[kk].z = wf[w0 + 512]; aw[kk].w = wf[w0 + 768];
    }
    if (tid < 128) bias_lds[tid] = bias[(size_t)b*8192 + tid*64 + f];
    __builtin_amdgcn_sched_barrier(0);

    // ---- A3: pack + store xt (2 positions per lane) ----
    #pragma unroll
    for (int it = 0; it < 2; ++it) {
        if (it == 0 || ln < 8) {
            int p0 = 2*ln + it*128;
            unsigned int w0[4], w1[4];
            #pragma unroll
            for (int jq = 0; jq < 4; ++jq) {
                float2 e0 = xv[it][2*jq], e1 = xv[it][2*jq + 1];
                w0[jq] = pack2(lrelu(e0.x), lrelu(e1.x));
                w1[jq] = pack2(lrelu(e0.y), lrelu(e1.y));
            }
            int a0 = ( p0     *128 + wv*16) ^ (( p0      & 7) << 4);
            int a1 = ((p0 + 1)*128 + wv*16) ^ (((p0 + 1) & 7) << 4);
            *(uint4*)(lds + a0) = make_uint4(w0[0], w0[1], w0[2], w0[3]);
            *(uint4*)(lds + a1) = make_uint4(w1[0], w1[1], w1[2], w1[3]);
        }
    }
    __syncthreads();

    // ---- B: dilated conv; wave (mt, nth); lean unroll-1 (R12) ----
    {
        float4 cb4 = *(const float4*)(conv_b + mt*16 + hi*4);
        const int n0  = nth ? 5 : 0;
        const int cnt = nth ? 4 : 5;                   // nt 0..4 | 5..8
        int bqa[6];
        #pragma unroll
        for (int kk = 0; kk < 6; ++kk) {
            int row = n0*16 + lo + 3*(kk >> 1) + 1;
            int cib = (kk & 1)*32 + hi*8;
            bqa[kk] = (row*128 + cib*2) ^ ((row & 7) << 4);
        }
        int hta = LDS_HT + (((n0*16 + lo)*128 + (mt*16 + hi*4)*2) ^ ((lo & 7) << 4));
        int pos = tb + n0*16 + lo - 8;
        #pragma unroll 1
        for (int i = 0; i < cnt; ++i) {
            f32x4 acc = {0.f, 0.f, 0.f, 0.f};
            __builtin_amdgcn_s_setprio(1);
            #pragma unroll
            for (int kk = 0; kk < 6; ++kk) {
                short8 bq = *(const short8*)(lds + bqa[kk]);
                acc = __builtin_amdgcn_mfma_f32_16x16x32_bf16(
                        __builtin_bit_cast(short8, aw[kk]), bq, acc, 0, 0, 0);
            }
            __builtin_amdgcn_s_setprio(0);

            bool valid = (unsigned)pos < 16384u;
            unsigned int h01 = valid ? pack2(lrelu(acc[0] + cb4.x), lrelu(acc[1] + cb4.y)) : 0u;
            unsigned int h23 = valid ? pack2(lrelu(acc[2] + cb4.z), lrelu(acc[3] + cb4.w)) : 0u;
            unsigned int* d = (unsigned int*)(lds + hta);
            d[0] = h01; d[1] = h23;

            #pragma unroll
            for (int kk = 0; kk < 6; ++kk) bqa[kk] += 2048;
            hta += 2048; pos += 16;
        }
    }

    // ---- issue am loads (phase C A-frags) so they drain at the barrier ----
    uint4v am[6];
    {
        const unsigned int* kp = ktf + (size_t)b*786432 + hi*8192 + f*128 + wv*16 + lo;
        #pragma unroll
        for (int kk = 0; kk < 6; ++kk) {
            int o = kk*131072;                         // jp stride 32768
            am[kk].x = kp[o        ]; am[kk].y = kp[o + 32768];
            am[kk].z = kp[o + 65536]; am[kk].w = kp[o + 98304];
        }
    }
    __syncthreads();

    // ---- C: LVC; wave wv owns GLU m-tile (same-lane pairs); ping-pong ----
    {
        const int ch2 = wv*8 + 2*hi;                   // this lane's channel pair
        float bs0 = bias_lds[ch2],      bs1 = bias_lds[ch2 + 1];
        float bt0 = bias_lds[ch2 + 64], bt1 = bias_lds[ch2 + 65];

        int bqa[6];
        #pragma unroll
        for (int kk = 0; kk < 6; ++kk) {
            int row = lo + 7 + (kk >> 1);
            int cib = (kk & 1)*32 + hi*8;
            bqa[kk] = LDS_HT + ((row*128 + cib*2) ^ ((row & 7) << 4));
        }
        const int q  = lo + 12;
        const int ra = (q*128 + ch2*2) ^ ((q & 7) << 4);
        float* ob = out + ((size_t)b*64 + ch2)*16384 + tb + lo;

        short8 cq[2][6];
        #pragma unroll
        for (int kk = 0; kk < 6; ++kk)
            cq[0][kk] = *(const short8*)(lds + bqa[kk]);

        #pragma unroll
        for (int i = 0; i < 8; ++i) {
            unsigned int rvc = *(const unsigned int*)(lds + ra + i*2048);
            if (i < 7) {
                #pragma unroll
                for (int kk = 0; kk < 6; ++kk)
                    cq[(i+1)&1][kk] = *(const short8*)(lds + bqa[kk] + (i+1)*2048);
            }
            f32x4 acc = {0.f, 0.f, 0.f, 0.f};
            __builtin_amdgcn_s_setprio(1);
            #pragma unroll
            for (int kk = 0; kk < 6; ++kk)
                acc = __builtin_amdgcn_mfma_f32_16x16x32_bf16(
                        __builtin_bit_cast(short8, am[kk]), cq[i&1][kk], acc, 0, 0, 0);
            __builtin_amdgcn_s_setprio(0);

            float h0 = bf2f(rvc & 0xFFFFu), h1 = bf2f(rvc >> 16);
            float g0 = glu_gate(acc[0] + bs0, acc[2] + bt0);
            float g1 = glu_gate(acc[1] + bs1, acc[3] + bt1);
            ob[(size_t)i*16]           = fminf(h0, 5.0f*h0) + g0;
            ob[16384 + (size_t)i*16]   = fminf(h1, 5.0f*h1) + g1;
        }
    }
}

extern "C" void kernel_launch(void* const* d_in, const int* in_sizes, int n_in,
                              void* d_out, int out_size, void* d_ws, size_t ws_size,
                              hipStream_t stream)
{
    const float* x      = (const float*)d_in[0];
    const float* kern   = (const float*)d_in[1];
    const float* bias   = (const float*)d_in[2];
    const float* conv_b = (const float*)d_in[4];
    float* out = (float*)d_out;

    if (ws_size < WS_NEED) return;   // harness provides >=100MB (verified R0)

    unsigned int* ktf = (unsigned int*)d_ws;
    unsigned int* wf  = (unsigned int*)((char*)d_ws + KTF_BYTES);

    wf_prep      <<<dim3(24),   dim3(TB), 0, stream>>>((const float*)d_in[3], wf);
    ktf_transpose<<<dim3(1536), dim3(TB), 0, stream>>>(kern, ktf);
    fused_kernel <<<dim3(2048), dim3(512), 0, stream>>>(x, bias, conv_b, ktf, wf, out);
    (void)in_sizes; (void)n_in; (void)out_size;
}